// Round 1
// baseline (439.416 us; speedup 1.0000x reference)
//
#include <hip/hip_runtime.h>
#include <cstdint>

typedef unsigned short u16;
typedef __bf16 bf16x8 __attribute__((ext_vector_type(8)));
typedef float f32x4 __attribute__((ext_vector_type(4)));

__device__ __forceinline__ u16 f2bf(float f) {
  unsigned u = __float_as_uint(f);
  u += 0x7fffu + ((u >> 16) & 1u);
  return (u16)(u >> 16);
}
__device__ __forceinline__ float bf2f(u16 h) {
  return __uint_as_float(((unsigned)h) << 16);
}

__device__ __forceinline__ void async16(const void* g, void* l) {
  __builtin_amdgcn_global_load_lds(
      (const __attribute__((address_space(1))) uint32_t*)g,
      (__attribute__((address_space(3))) uint32_t*)l, 16, 0, 0);
}

// ---------------- convert x f32 -> bf16, 4 elems/thread ----------------
__global__ void k_cvt(const float* __restrict__ in, u16* __restrict__ out, int n4) {
  int i = blockIdx.x * blockDim.x + threadIdx.x;
  if (i >= n4) return;
  const float4 v = ((const float4*)in)[i];
  ushort4 o;
  o.x = f2bf(v.x); o.y = f2bf(v.y); o.z = f2bf(v.z); o.w = f2bf(v.w);
  ((ushort4*)out)[i] = o;
}

// ---------------- transpose (+convert) to bf16 ----------------
__device__ __forceinline__ u16 to_bf(float v) { return f2bf(v); }
__device__ __forceinline__ u16 to_bf(u16 v) { return v; }

template <typename Tin>
__global__ void k_transpose(const Tin* __restrict__ in, u16* __restrict__ out,
                            int lda, int ldo, long bsIn, long bsOut) {
  __shared__ u16 tile[32][33];
  const int b = blockIdx.z;
  in += (size_t)b * bsIn;
  out += (size_t)b * bsOut;
  const int c0 = blockIdx.x * 32, r0 = blockIdx.y * 32;
  const int tx = threadIdx.x, ty = threadIdx.y;  // block (32,8)
#pragma unroll
  for (int i = 0; i < 4; ++i) {
    int r = r0 + ty + i * 8;
    tile[ty + i * 8][tx] = to_bf(in[(size_t)r * lda + c0 + tx]);
  }
  __syncthreads();
#pragma unroll
  for (int i = 0; i < 4; ++i) {
    out[(size_t)(c0 + ty + i * 8) * ldo + r0 + tx] = tile[tx][ty + i * 8];
  }
}

// ---------------- row sums of P (bf16), one wave per row ----------------
__global__ void k_rowsum(const u16* __restrict__ P, float* __restrict__ lsum) {
  const int w = threadIdx.x >> 6, l = threadIdx.x & 63;
  const int row = blockIdx.x * 4 + w;
  const u16* pr = P + (size_t)row * 2048;
  float s = 0.f;
#pragma unroll
  for (int j = 0; j < 4; ++j) {
    bf16x8 v = *(const bf16x8*)(pr + j * 512 + l * 8);
#pragma unroll
    for (int e = 0; e < 8; ++e) s += (float)v[e];
  }
#pragma unroll
  for (int off = 32; off > 0; off >>= 1) s += __shfl_down(s, off, 64);
  if (l == 0) lsum[row] = s;
}

// ---------------- BT GEMM: C[M,N] = A[M,K] * Bt[N,K]^T  (all bf16 in, fp32 acc)
// MODE 0: +bias[col]; cols<1024 scaled by 1/32 (q prescale); write bf16 (qkv)
// MODE 1: mask+exp -> bf16 P
// MODE 2: /lsum[row] -> bf16 ctx
// MODE 3: +bias[col] -> fp32 out
template <int MODE>
__global__ __launch_bounds__(256) void gemm_bt(
    const u16* __restrict__ A, long lda, long bsA,
    const u16* __restrict__ Bt, long ldb, long bsB,
    void* __restrict__ C, long ldc, long bsC,
    int M, int N, int K,
    const float* __restrict__ bias, const int* __restrict__ mask,
    const float* __restrict__ lsum) {
  __shared__ u16 As[128 * 32];
  __shared__ u16 Bs[128 * 32];

  const int b = blockIdx.z;
  const int m0 = blockIdx.y * 128, n0 = blockIdx.x * 128;
  const int lane = threadIdx.x & 63;
  const int w = threadIdx.x >> 6;
  const int wr = w >> 1, wc = w & 1;

  // staging lane geometry: 16 rows x 4 chunks of 16B per wave-call
  const int srow = lane >> 2;
  const int scol = (lane & 3) * 8;
  const u16* pa = A + (size_t)b * bsA + (size_t)(m0 + srow) * lda + scol;
  const u16* pb = Bt + (size_t)b * bsB + (size_t)(n0 + srow) * ldb + scol;

  // fragment LDS addresses
  const int koff = (lane >> 4) * 8;
  const u16* aAddr = As + (wr * 64 + (lane & 15)) * 32 + koff;
  const u16* bAddr = Bs + (wc * 64 + (lane & 15)) * 32 + koff;

  f32x4 acc[4][4] = {};

  for (int kt = 0; kt < K; kt += 32) {
    __syncthreads();
#pragma unroll
    for (int g = 0; g < 2; ++g) {
      const int rg = (w * 2 + g) * 16;
      async16(pa + (size_t)rg * lda, As + rg * 32);
      async16(pb + (size_t)rg * ldb, Bs + rg * 32);
    }
    __syncthreads();
    bf16x8 af[4], bfr[4];
#pragma unroll
    for (int t = 0; t < 4; ++t) af[t] = *(const bf16x8*)(aAddr + t * 512);
#pragma unroll
    for (int t = 0; t < 4; ++t) bfr[t] = *(const bf16x8*)(bAddr + t * 512);
#pragma unroll
    for (int mt = 0; mt < 4; ++mt)
#pragma unroll
      for (int nt = 0; nt < 4; ++nt)
        acc[mt][nt] = __builtin_amdgcn_mfma_f32_16x16x32_bf16(af[mt], bfr[nt], acc[mt][nt], 0, 0, 0);
    pa += 32;
    pb += 32;
  }

  // epilogue: C/D layout col=lane&15, row=(lane>>4)*4+reg
#pragma unroll
  for (int mt = 0; mt < 4; ++mt) {
#pragma unroll
    for (int nt = 0; nt < 4; ++nt) {
      const int col = n0 + wc * 64 + nt * 16 + (lane & 15);
      const int row0 = m0 + wr * 64 + mt * 16 + ((lane >> 4) << 2);
#pragma unroll
      for (int r = 0; r < 4; ++r) {
        const int row = row0 + r;
        float v = acc[mt][nt][r];
        if constexpr (MODE == 0) {
          v += bias[col];
          if (col < 1024) v *= 0.03125f;
          ((u16*)C)[(size_t)b * bsC + (size_t)row * ldc + col] = f2bf(v);
        } else if constexpr (MODE == 1) {
          const int mk = mask[((size_t)b * M + row) * (size_t)N + col];
          v = mk ? __expf(fminf(v, 80.f)) : 0.f;
          ((u16*)C)[(size_t)b * bsC + (size_t)row * ldc + col] = f2bf(v);
        } else if constexpr (MODE == 2) {
          v = v / lsum[(size_t)b * M + row];
          ((u16*)C)[(size_t)b * bsC + (size_t)row * ldc + col] = f2bf(v);
        } else {
          v += bias[col];
          ((float*)C)[(size_t)b * bsC + (size_t)row * ldc + col] = v;
        }
      }
    }
  }
}

extern "C" void kernel_launch(void* const* d_in, const int* in_sizes, int n_in,
                              void* d_out, int out_size, void* d_ws, size_t ws_size,
                              hipStream_t stream) {
  const float* x = (const float*)d_in[0];
  const int* mask = (const int*)d_in[1];
  const float* proj_w = (const float*)d_in[2];
  const float* proj_b = (const float*)d_in[3];
  const float* out_w = (const float*)d_in[4];
  const float* out_b = (const float*)d_in[5];
  float* out = (float*)d_out;

  // workspace layout (bytes); total ~120 MB
  char* ws = (char*)d_ws;
  u16* xb = (u16*)(ws);                      // 16.8 MB  [8192][1024]
  u16* wt = (u16*)(ws + 16777216);           // 6.3 MB   [3072][1024]
  u16* owt = (u16*)(ws + 23068672);          // 2.1 MB   [1024][1024]
  u16* qkv = (u16*)(ws + 25165824);          // 50.3 MB  [8192][3072]
  u16* P = (u16*)(ws + 75497472);            // 33.6 MB  [4][2048][2048]
  u16* Vt = (u16*)(ws + 109051904);          // 16.8 MB  [4][1024][2048]
  float* lsum = (float*)(ws + 125829120);    // 32 KB    [8192]
  u16* ctx = xb;                             // alias: xb dead after gemm<0>

  // 1. x -> bf16
  k_cvt<<<8192, 256, 0, stream>>>(x, xb, 2097152);
  // 2. proj_w [1024][3072] -> wt [3072][1024] (bf16)
  k_transpose<float><<<dim3(96, 32, 1), dim3(32, 8), 0, stream>>>(proj_w, wt, 3072, 1024, 0, 0);
  // 3. out_w [1024][1024] -> owt (bf16)
  k_transpose<float><<<dim3(32, 32, 1), dim3(32, 8), 0, stream>>>(out_w, owt, 1024, 1024, 0, 0);
  // 4. qkv = x @ proj_w + b  (q part prescaled by 1/32)
  gemm_bt<0><<<dim3(24, 64, 1), 256, 0, stream>>>(xb, 1024, 0, wt, 1024, 0, qkv, 3072, 0,
                                                  8192, 3072, 1024, proj_b, nullptr, nullptr);
  // 5. V [2048][1024] (stride 3072) -> Vt [1024][2048], per batch
  k_transpose<u16><<<dim3(32, 64, 4), dim3(32, 8), 0, stream>>>(
      qkv + 2048, Vt, 3072, 2048, (long)2048 * 3072, (long)1024 * 2048);
  // 6. P = mask ? exp(q k^T / sqrt(E)) : 0
  gemm_bt<1><<<dim3(16, 16, 4), 256, 0, stream>>>(
      qkv, 3072, (long)2048 * 3072, qkv + 1024, 3072, (long)2048 * 3072,
      P, 2048, (long)2048 * 2048, 2048, 2048, 1024, nullptr, mask, nullptr);
  // 7. row sums of P
  k_rowsum<<<2048, 256, 0, stream>>>(P, lsum);
  // 8. ctx = (P @ V) / l
  gemm_bt<2><<<dim3(8, 16, 4), 256, 0, stream>>>(
      P, 2048, (long)2048 * 2048, Vt, 2048, (long)1024 * 2048,
      ctx, 1024, (long)2048 * 1024, 2048, 1024, 2048, nullptr, nullptr, lsum);
  // 9. out = ctx @ out_w + out_b (fp32)
  gemm_bt<3><<<dim3(8, 64, 1), 256, 0, stream>>>(ctx, 1024, 0, owt, 1024, 0, out, 1024, 0,
                                                 8192, 1024, 1024, out_b, nullptr, nullptr);
}

// Round 2
// 350.253 us; speedup vs baseline: 1.2546x; 1.2546x over previous
//
#include <hip/hip_runtime.h>
#include <cstdint>

typedef unsigned short u16;
typedef __bf16 bf16x8 __attribute__((ext_vector_type(8)));
typedef float f32x4 __attribute__((ext_vector_type(4)));

__device__ __forceinline__ u16 f2bf(float f) {
  unsigned u = __float_as_uint(f);
  u += 0x7fffu + ((u >> 16) & 1u);
  return (u16)(u >> 16);
}

__device__ __forceinline__ void async16(const void* g, void* l) {
  __builtin_amdgcn_global_load_lds(
      (const __attribute__((address_space(1))) uint32_t*)g,
      (__attribute__((address_space(3))) uint32_t*)l, 16, 0, 0);
}

// ---------------- convert x f32 -> bf16, 4 elems/thread ----------------
__global__ void k_cvt(const float* __restrict__ in, u16* __restrict__ out, int n4) {
  int i = blockIdx.x * blockDim.x + threadIdx.x;
  if (i >= n4) return;
  const float4 v = ((const float4*)in)[i];
  ushort4 o;
  o.x = f2bf(v.x); o.y = f2bf(v.y); o.z = f2bf(v.z); o.w = f2bf(v.w);
  ((ushort4*)out)[i] = o;
}

// ---------------- transpose (+convert) to bf16 ----------------
__device__ __forceinline__ u16 to_bf(float v) { return f2bf(v); }
__device__ __forceinline__ u16 to_bf(u16 v) { return v; }

template <typename Tin>
__global__ void k_transpose(const Tin* __restrict__ in, u16* __restrict__ out,
                            int lda, int ldo, long bsIn, long bsOut) {
  __shared__ u16 tile[32][33];
  const int b = blockIdx.z;
  in += (size_t)b * bsIn;
  out += (size_t)b * bsOut;
  const int c0 = blockIdx.x * 32, r0 = blockIdx.y * 32;
  const int tx = threadIdx.x, ty = threadIdx.y;  // block (32,8)
#pragma unroll
  for (int i = 0; i < 4; ++i) {
    int r = r0 + ty + i * 8;
    tile[ty + i * 8][tx] = to_bf(in[(size_t)r * lda + c0 + tx]);
  }
  __syncthreads();
#pragma unroll
  for (int i = 0; i < 4; ++i) {
    out[(size_t)(c0 + ty + i * 8) * ldo + r0 + tx] = tile[tx][ty + i * 8];
  }
}

// ------- streaming mask+exp+rowsum, in-place on score buffer -------
// SP: [8192][2048] bf16 scores in, P out. mask: [8192][2048] int32.
__global__ __launch_bounds__(256) void k_maskexp(u16* __restrict__ SP,
                                                 const int* __restrict__ mask,
                                                 float* __restrict__ lsum) {
  const int w = threadIdx.x >> 6, lane = threadIdx.x & 63;
  const int row = blockIdx.x * 4 + w;
  const size_t base = (size_t)row * 2048;
  float s = 0.f;
#pragma unroll
  for (int c = 0; c < 4; ++c) {
    const size_t idx = base + c * 512 + lane * 8;
    bf16x8 v = *(const bf16x8*)(SP + idx);
    const int4 m0 = *(const int4*)(mask + idx);
    const int4 m1 = *(const int4*)(mask + idx + 4);
    float e[8];
    const int mk[8] = {m0.x, m0.y, m0.z, m0.w, m1.x, m1.y, m1.z, m1.w};
#pragma unroll
    for (int j = 0; j < 8; ++j) {
      float f = __expf(fminf((float)v[j], 80.f));
      e[j] = mk[j] ? f : 0.f;
      s += e[j];
      v[j] = (__bf16)e[j];
    }
    *(bf16x8*)(SP + idx) = v;
  }
#pragma unroll
  for (int off = 32; off > 0; off >>= 1) s += __shfl_down(s, off, 64);
  if (lane == 0) lsum[row] = s;
}

// ---------------- BT GEMM: C[M,N] = A[M,K] * Bt[N,K]^T  (bf16 in, fp32 acc)
// 128x128 tile, BK=64, XOR-swizzled LDS (chunk slot = logical ^ (row&7)).
// MODE 0: +bias[col]; cols<1024 scaled by 1/32 (q prescale); write bf16 (qkv)
// MODE 1: plain bf16 store (raw scores)
// MODE 2: /lsum[row] -> bf16 ctx
// MODE 3: +bias[col] -> fp32 out
template <int MODE>
__global__ __launch_bounds__(256) void gemm_bt(
    const u16* __restrict__ A, long lda, long bsA,
    const u16* __restrict__ Bt, long ldb, long bsB,
    void* __restrict__ C, long ldc, long bsC,
    int M, int N, int K,
    const float* __restrict__ bias, const float* __restrict__ lsum) {
  __shared__ u16 As[128 * 64];  // 16 KB, row stride 64 u16, chunks of 8 u16 swizzled
  __shared__ u16 Bs[128 * 64];

  const int b = blockIdx.z;
  const int m0 = blockIdx.y * 128, n0 = blockIdx.x * 128;
  const int lane = threadIdx.x & 63;
  const int w = threadIdx.x >> 6;
  const int wr = w >> 1, wc = w & 1;

  // staging geometry: one async16 call covers 8 rows x 64 u16.
  // lane L -> row (L>>3), slot (L&7); global chunk = slot ^ (row&7)
  const int srow = lane >> 3;
  const int scol = ((lane & 7) ^ (lane >> 3 & 7)) * 8;
  const u16* pa = A + (size_t)b * bsA + (size_t)(m0 + srow) * lda + scol;
  const u16* pb = Bt + (size_t)b * bsB + (size_t)(n0 + srow) * ldb + scol;

  // fragment read geometry (16x16x32, A/B operand: lane m=lane&15 holds 8
  // contiguous k at k0=(lane>>4)*8). logical chunk l = s*4+q; phys = l^(m&7).
  const int m_l = lane & 15, q = lane >> 4, m7 = m_l & 7;
  const int offs[2] = {(q ^ m7) * 8, ((4 + q) ^ m7) * 8};

  f32x4 acc[4][4] = {};

  for (int kt = 0; kt < K; kt += 64) {
    __syncthreads();
#pragma unroll
    for (int g = 0; g < 4; ++g) {
      const int c = w * 4 + g;  // call index 0..15, rows c*8..c*8+7
      async16(pa + (size_t)(c * 8) * lda, As + c * 512);
      async16(pb + (size_t)(c * 8) * ldb, Bs + c * 512);
    }
    __syncthreads();
#pragma unroll
    for (int s = 0; s < 2; ++s) {
      bf16x8 af[4], bfr[4];
#pragma unroll
      for (int t = 0; t < 4; ++t)
        af[t] = *(const bf16x8*)(As + (wr * 64 + t * 16 + m_l) * 64 + offs[s]);
#pragma unroll
      for (int t = 0; t < 4; ++t)
        bfr[t] = *(const bf16x8*)(Bs + (wc * 64 + t * 16 + m_l) * 64 + offs[s]);
#pragma unroll
      for (int mt = 0; mt < 4; ++mt)
#pragma unroll
        for (int nt = 0; nt < 4; ++nt)
          acc[mt][nt] = __builtin_amdgcn_mfma_f32_16x16x32_bf16(af[mt], bfr[nt], acc[mt][nt], 0, 0, 0);
    }
    pa += 64;
    pb += 64;
  }

  // epilogue: C/D layout col=lane&15, row=(lane>>4)*4+reg
#pragma unroll
  for (int mt = 0; mt < 4; ++mt) {
#pragma unroll
    for (int nt = 0; nt < 4; ++nt) {
      const int col = n0 + wc * 64 + nt * 16 + (lane & 15);
      const int row0 = m0 + wr * 64 + mt * 16 + ((lane >> 4) << 2);
#pragma unroll
      for (int r = 0; r < 4; ++r) {
        const int row = row0 + r;
        float v = acc[mt][nt][r];
        if constexpr (MODE == 0) {
          v += bias[col];
          if (col < 1024) v *= 0.03125f;
          ((u16*)C)[(size_t)b * bsC + (size_t)row * ldc + col] = f2bf(v);
        } else if constexpr (MODE == 1) {
          ((u16*)C)[(size_t)b * bsC + (size_t)row * ldc + col] = f2bf(v);
        } else if constexpr (MODE == 2) {
          v = v / lsum[(size_t)b * M + row];
          ((u16*)C)[(size_t)b * bsC + (size_t)row * ldc + col] = f2bf(v);
        } else {
          v += bias[col];
          ((float*)C)[(size_t)b * bsC + (size_t)row * ldc + col] = v;
        }
      }
    }
  }
}

extern "C" void kernel_launch(void* const* d_in, const int* in_sizes, int n_in,
                              void* d_out, int out_size, void* d_ws, size_t ws_size,
                              hipStream_t stream) {
  const float* x = (const float*)d_in[0];
  const int* mask = (const int*)d_in[1];
  const float* proj_w = (const float*)d_in[2];
  const float* proj_b = (const float*)d_in[3];
  const float* out_w = (const float*)d_in[4];
  const float* out_b = (const float*)d_in[5];
  float* out = (float*)d_out;

  // workspace layout (bytes); total ~126 MB
  char* ws = (char*)d_ws;
  u16* xb = (u16*)(ws);                      // 16.8 MB  [8192][1024]
  u16* wt = (u16*)(ws + 16777216);           // 6.3 MB   [3072][1024]
  u16* owt = (u16*)(ws + 23068672);          // 2.1 MB   [1024][1024]
  u16* qkv = (u16*)(ws + 25165824);          // 50.3 MB  [8192][3072]
  u16* P = (u16*)(ws + 75497472);            // 33.6 MB  [4][2048][2048] (scores, then exp in-place)
  u16* Vt = (u16*)(ws + 109051904);          // 16.8 MB  [4][1024][2048]
  float* lsum = (float*)(ws + 125829120);    // 32 KB    [8192]
  u16* ctx = xb;                             // alias: xb dead after gemm<0>

  // 1. x -> bf16
  k_cvt<<<8192, 256, 0, stream>>>(x, xb, 2097152);
  // 2. proj_w [1024][3072] -> wt [3072][1024] (bf16)
  k_transpose<float><<<dim3(96, 32, 1), dim3(32, 8), 0, stream>>>(proj_w, wt, 3072, 1024, 0, 0);
  // 3. out_w [1024][1024] -> owt (bf16)
  k_transpose<float><<<dim3(32, 32, 1), dim3(32, 8), 0, stream>>>(out_w, owt, 1024, 1024, 0, 0);
  // 4. qkv = x @ proj_w + b  (q part prescaled by 1/32)
  gemm_bt<0><<<dim3(24, 64, 1), 256, 0, stream>>>(xb, 1024, 0, wt, 1024, 0, qkv, 3072, 0,
                                                  8192, 3072, 1024, proj_b, nullptr);
  // 5. V [2048][1024] (stride 3072) -> Vt [1024][2048], per batch
  k_transpose<u16><<<dim3(32, 64, 4), dim3(32, 8), 0, stream>>>(
      qkv + 2048, Vt, 3072, 2048, (long)2048 * 3072, (long)1024 * 2048);
  // 6. S = q k^T / sqrt(E) (raw scores, bf16)
  gemm_bt<1><<<dim3(16, 16, 4), 256, 0, stream>>>(
      qkv, 3072, (long)2048 * 3072, qkv + 1024, 3072, (long)2048 * 3072,
      P, 2048, (long)2048 * 2048, 2048, 2048, 1024, nullptr, nullptr);
  // 7. P = mask ? exp(S) : 0, in-place; row sums -> lsum
  k_maskexp<<<2048, 256, 0, stream>>>(P, mask, lsum);
  // 8. ctx = (P @ V) / l
  gemm_bt<2><<<dim3(8, 16, 4), 256, 0, stream>>>(
      P, 2048, (long)2048 * 2048, Vt, 2048, (long)1024 * 2048,
      ctx, 1024, (long)2048 * 1024, 2048, 1024, 2048, nullptr, lsum);
  // 9. out = ctx @ out_w + out_b (fp32)
  gemm_bt<3><<<dim3(8, 64, 1), 256, 0, stream>>>(ctx, 1024, 0, owt, 1024, 0, out, 1024, 0,
                                                 8192, 1024, 1024, out_b, nullptr);
}

// Round 3
// 349.434 us; speedup vs baseline: 1.2575x; 1.0023x over previous
//
#include <hip/hip_runtime.h>
#include <cstdint>

typedef unsigned short u16;
typedef uint32_t u32;
typedef __bf16 bf16x8 __attribute__((ext_vector_type(8)));
typedef float f32x4 __attribute__((ext_vector_type(4)));

__device__ __forceinline__ u16 f2bf(float f) {
  unsigned u = __float_as_uint(f);
  u += 0x7fffu + ((u >> 16) & 1u);
  return (u16)(u >> 16);
}

__device__ __forceinline__ void async16(const void* g, void* l) {
  __builtin_amdgcn_global_load_lds(
      (const __attribute__((address_space(1))) uint32_t*)g,
      (__attribute__((address_space(3))) uint32_t*)l, 16, 0, 0);
}

// ---------------- convert x f32 -> bf16, 4 elems/thread ----------------
__global__ void k_cvt(const float* __restrict__ in, u16* __restrict__ out, int n4) {
  int i = blockIdx.x * blockDim.x + threadIdx.x;
  if (i >= n4) return;
  const float4 v = ((const float4*)in)[i];
  ushort4 o;
  o.x = f2bf(v.x); o.y = f2bf(v.y); o.z = f2bf(v.z); o.w = f2bf(v.w);
  ((ushort4*)out)[i] = o;
}

// ---------------- transpose (+convert) to bf16 ----------------
__device__ __forceinline__ u16 to_bf(float v) { return f2bf(v); }
__device__ __forceinline__ u16 to_bf(u16 v) { return v; }

template <typename Tin>
__global__ void k_transpose(const Tin* __restrict__ in, u16* __restrict__ out,
                            int lda, int ldo, long bsIn, long bsOut) {
  __shared__ u16 tile[32][33];
  const int b = blockIdx.z;
  in += (size_t)b * bsIn;
  out += (size_t)b * bsOut;
  const int c0 = blockIdx.x * 32, r0 = blockIdx.y * 32;
  const int tx = threadIdx.x, ty = threadIdx.y;  // block (32,8)
#pragma unroll
  for (int i = 0; i < 4; ++i) {
    int r = r0 + ty + i * 8;
    tile[ty + i * 8][tx] = to_bf(in[(size_t)r * lda + c0 + tx]);
  }
  __syncthreads();
#pragma unroll
  for (int i = 0; i < 4; ++i) {
    out[(size_t)(c0 + ty + i * 8) * ldo + r0 + tx] = tile[tx][ty + i * 8];
  }
}

// ---------------- bit-pack mask: 32 int32 -> 1 u32 word ----------------
// word w covers flat elements [w*32, w*32+32); flat = (b*2048+row)*2048+col.
__global__ __launch_bounds__(256) void k_bitpack(const int* __restrict__ mask,
                                                 u32* __restrict__ mbits) {
  const size_t w = (size_t)blockIdx.x * 256 + threadIdx.x;
  const int* p = mask + w * 32;
  u32 bits = 0;
#pragma unroll
  for (int j = 0; j < 8; ++j) {
    const int4 v = ((const int4*)p)[j];
    bits |= (u32)(v.x & 1) << (j * 4 + 0);
    bits |= (u32)(v.y & 1) << (j * 4 + 1);
    bits |= (u32)(v.z & 1) << (j * 4 + 2);
    bits |= (u32)(v.w & 1) << (j * 4 + 3);
  }
  mbits[w] = bits;
}

// ---------------- BT GEMM: C[M,N] = A[M,K] * Bt[N,K]^T  (bf16 in, fp32 acc)
// 128x128 tile, BK=64, XOR-swizzled LDS (chunk slot = logical ^ (row&7)).
// MODE 0: +bias[col]; cols<1024 scaled by 1/32 (q prescale); write bf16 (qkv)
// MODE 1: mask(bitpacked)+exp -> bf16 P (fused softmax numerator)
// MODE 2: ones-MFMA row sums; /rowsum -> bf16 ctx
// MODE 3: +bias[col] -> fp32 out
template <int MODE>
__global__ __launch_bounds__(256) void gemm_bt(
    const u16* __restrict__ A, long lda, long bsA,
    const u16* __restrict__ Bt, long ldb, long bsB,
    void* __restrict__ C, long ldc, long bsC,
    int M, int N, int K,
    const float* __restrict__ bias, const u32* __restrict__ mbits) {
  __shared__ u16 As[128 * 64];  // 16 KB, row stride 64 u16, 8-u16 chunks swizzled
  __shared__ u16 Bs[128 * 64];

  const int b = blockIdx.z;
  const int m0 = blockIdx.y * 128, n0 = blockIdx.x * 128;
  const int lane = threadIdx.x & 63;
  const int w = threadIdx.x >> 6;
  const int wr = w >> 1, wc = w & 1;

  // staging geometry: one async16 call covers 8 rows x 64 u16.
  // lane L -> row (L>>3), slot (L&7); global chunk = slot ^ (row&7)
  const int srow = lane >> 3;
  const int scol = ((lane & 7) ^ ((lane >> 3) & 7)) * 8;
  const u16* pa = A + (size_t)b * bsA + (size_t)(m0 + srow) * lda + scol;
  const u16* pb = Bt + (size_t)b * bsB + (size_t)(n0 + srow) * ldb + scol;

  // fragment read geometry (16x16x32 A/B operand: lane m=lane&15 holds 8
  // contiguous k at k0=(lane>>4)*8). logical chunk l = s*4+q; phys = l^(m&7).
  const int m_l = lane & 15, q = lane >> 4, m7 = m_l & 7;
  const int offs[2] = {(q ^ m7) * 8, ((4 + q) ^ m7) * 8};

  f32x4 acc[4][4] = {};
  f32x4 accs[4] = {};  // MODE 2: per-mt row-sum accumulator (C layout)
  bf16x8 ones;
#pragma unroll
  for (int e = 0; e < 8; ++e) ones[e] = (__bf16)1.0f;

  for (int kt = 0; kt < K; kt += 64) {
    __syncthreads();
#pragma unroll
    for (int g = 0; g < 4; ++g) {
      const int c = w * 4 + g;  // call index 0..15, rows c*8..c*8+7
      async16(pa + (size_t)(c * 8) * lda, As + c * 512);
      async16(pb + (size_t)(c * 8) * ldb, Bs + c * 512);
    }
    __syncthreads();
#pragma unroll
    for (int s = 0; s < 2; ++s) {
      bf16x8 af[4], bfr[4];
#pragma unroll
      for (int t = 0; t < 4; ++t)
        af[t] = *(const bf16x8*)(As + (wr * 64 + t * 16 + m_l) * 64 + offs[s]);
#pragma unroll
      for (int t = 0; t < 4; ++t)
        bfr[t] = *(const bf16x8*)(Bs + (wc * 64 + t * 16 + m_l) * 64 + offs[s]);
#pragma unroll
      for (int mt = 0; mt < 4; ++mt)
#pragma unroll
        for (int nt = 0; nt < 4; ++nt)
          acc[mt][nt] = __builtin_amdgcn_mfma_f32_16x16x32_bf16(af[mt], bfr[nt], acc[mt][nt], 0, 0, 0);
      if constexpr (MODE == 2) {
#pragma unroll
        for (int mt = 0; mt < 4; ++mt)
          accs[mt] = __builtin_amdgcn_mfma_f32_16x16x32_bf16(af[mt], ones, accs[mt], 0, 0, 0);
      }
    }
    pa += 64;
    pb += 64;
  }

  // MODE 1: stage this block's mask bits (128 rows x 4 words) into LDS
  if constexpr (MODE == 1) {
    __syncthreads();  // all waves done reading As
    const int rl = threadIdx.x >> 1, pr = threadIdx.x & 1;
    const uint2 v = *(const uint2*)(mbits + ((size_t)(b * M + m0 + rl)) * (N >> 5) + (n0 >> 5) + pr * 2);
    ((u32*)As)[rl * 4 + pr * 2] = v.x;
    ((u32*)As)[rl * 4 + pr * 2 + 1] = v.y;
    __syncthreads();
  }

  // MODE 2: reciprocals of row sums (same C-layout slots as acc rows)
  float rinv[4][4];
  if constexpr (MODE == 2) {
#pragma unroll
    for (int mt = 0; mt < 4; ++mt)
#pragma unroll
      for (int r = 0; r < 4; ++r) rinv[mt][r] = 1.0f / accs[mt][r];
  }

  // epilogue: C/D layout col=lane&15, row=(lane>>4)*4+reg
#pragma unroll
  for (int mt = 0; mt < 4; ++mt) {
#pragma unroll
    for (int nt = 0; nt < 4; ++nt) {
      const int col = n0 + wc * 64 + nt * 16 + m_l;
      const int row0 = m0 + wr * 64 + mt * 16 + q * 4;
#pragma unroll
      for (int r = 0; r < 4; ++r) {
        const int row = row0 + r;
        float v = acc[mt][nt][r];
        if constexpr (MODE == 0) {
          v += bias[col];
          if (col < 1024) v *= 0.03125f;
          ((u16*)C)[(size_t)b * bsC + (size_t)row * ldc + col] = f2bf(v);
        } else if constexpr (MODE == 1) {
          const int cl = wc * 64 + nt * 16 + m_l;
          const int rl = wr * 64 + mt * 16 + q * 4 + r;
          const u32 wb = ((const u32*)As)[rl * 4 + (cl >> 5)];
          v = ((wb >> (cl & 31)) & 1u) ? __expf(fminf(v, 30.f)) : 0.f;
          ((u16*)C)[(size_t)b * bsC + (size_t)row * ldc + col] = f2bf(v);
        } else if constexpr (MODE == 2) {
          v *= rinv[mt][r];
          ((u16*)C)[(size_t)b * bsC + (size_t)row * ldc + col] = f2bf(v);
        } else {
          v += bias[col];
          ((float*)C)[(size_t)b * bsC + (size_t)row * ldc + col] = v;
        }
      }
    }
  }
}

extern "C" void kernel_launch(void* const* d_in, const int* in_sizes, int n_in,
                              void* d_out, int out_size, void* d_ws, size_t ws_size,
                              hipStream_t stream) {
  const float* x = (const float*)d_in[0];
  const int* mask = (const int*)d_in[1];
  const float* proj_w = (const float*)d_in[2];
  const float* proj_b = (const float*)d_in[3];
  const float* out_w = (const float*)d_in[4];
  const float* out_b = (const float*)d_in[5];
  float* out = (float*)d_out;

  // workspace layout (bytes); total ~126 MB
  char* ws = (char*)d_ws;
  u16* xb = (u16*)(ws);                      // 16.8 MB  [8192][1024]
  u16* wt = (u16*)(ws + 16777216);           // 6.3 MB   [3072][1024]
  u16* owt = (u16*)(ws + 23068672);          // 2.1 MB   [1024][1024]
  u16* qkv = (u16*)(ws + 25165824);          // 50.3 MB  [8192][3072]
  u16* P = (u16*)(ws + 75497472);            // 33.6 MB  [4][2048][2048]
  u16* Vt = (u16*)(ws + 109051904);          // 16.8 MB  [4][1024][2048]
  u16* ctx = xb;                             // alias: xb dead after gemm<0>
  u32* mbits = (u32*)wt;                     // alias: wt dead after gemm<0> (2.1 MB)

  // 1. x -> bf16
  k_cvt<<<8192, 256, 0, stream>>>(x, xb, 2097152);
  // 2. proj_w [1024][3072] -> wt [3072][1024] (bf16)
  k_transpose<float><<<dim3(96, 32, 1), dim3(32, 8), 0, stream>>>(proj_w, wt, 3072, 1024, 0, 0);
  // 3. out_w [1024][1024] -> owt (bf16)
  k_transpose<float><<<dim3(32, 32, 1), dim3(32, 8), 0, stream>>>(out_w, owt, 1024, 1024, 0, 0);
  // 4. qkv = x @ proj_w + b  (q part prescaled by 1/32)
  gemm_bt<0><<<dim3(24, 64, 1), 256, 0, stream>>>(xb, 1024, 0, wt, 1024, 0, qkv, 3072, 0,
                                                  8192, 3072, 1024, proj_b, nullptr);
  // 5. mask -> bit-packed (overlays wt, dead after step 4)
  k_bitpack<<<2048, 256, 0, stream>>>(mask, mbits);
  // 6. V [2048][1024] (stride 3072) -> Vt [1024][2048], per batch
  k_transpose<u16><<<dim3(32, 64, 4), dim3(32, 8), 0, stream>>>(
      qkv + 2048, Vt, 3072, 2048, (long)2048 * 3072, (long)1024 * 2048);
  // 7. P = mask ? exp(q k^T / sqrt(E)) : 0   (fused epilogue)
  gemm_bt<1><<<dim3(16, 16, 4), 256, 0, stream>>>(
      qkv, 3072, (long)2048 * 3072, qkv + 1024, 3072, (long)2048 * 3072,
      P, 2048, (long)2048 * 2048, 2048, 2048, 1024, nullptr, mbits);
  // 8. ctx = (P @ V) / rowsum   (rowsum via ones-MFMA, in-block)
  gemm_bt<2><<<dim3(8, 16, 4), 256, 0, stream>>>(
      P, 2048, (long)2048 * 2048, Vt, 2048, (long)1024 * 2048,
      ctx, 1024, (long)2048 * 1024, 2048, 1024, 2048, nullptr, nullptr);
  // 9. out = ctx @ out_w + out_b (fp32)
  gemm_bt<3><<<dim3(8, 64, 1), 256, 0, stream>>>(ctx, 1024, 0, owt, 1024, 0, out, 1024, 0,
                                                 8192, 1024, 1024, out_b, nullptr);
}

// Round 4
// 345.376 us; speedup vs baseline: 1.2723x; 1.0117x over previous
//
#include <hip/hip_runtime.h>
#include <cstdint>

typedef unsigned short u16;
typedef uint32_t u32;
typedef __bf16 bf16x8 __attribute__((ext_vector_type(8)));
typedef float f32x4 __attribute__((ext_vector_type(4)));

__device__ __forceinline__ u16 f2bf(float f) {
  unsigned u = __float_as_uint(f);
  u += 0x7fffu + ((u >> 16) & 1u);
  return (u16)(u >> 16);
}

__device__ __forceinline__ void async16(const void* g, void* l) {
  __builtin_amdgcn_global_load_lds(
      (const __attribute__((address_space(1))) uint32_t*)g,
      (__attribute__((address_space(3))) uint32_t*)l, 16, 0, 0);
}

// ------------- fused prep: x->bf16 | proj_w^T -> bf16 | out_w^T -> bf16 -----
// grid: [0,8192) cvt; [8192,11264) proj_w transpose; [11264,12288) out_w transpose
__global__ __launch_bounds__(256) void k_prep(const float* __restrict__ x, u16* __restrict__ xb,
                                              const float* __restrict__ pw, u16* __restrict__ wt,
                                              const float* __restrict__ ow, u16* __restrict__ owt) {
  const int bid = blockIdx.x;
  if (bid < 8192) {
    const int i = bid * 256 + threadIdx.x;
    const float4 v = ((const float4*)x)[i];
    ushort4 o;
    o.x = f2bf(v.x); o.y = f2bf(v.y); o.z = f2bf(v.z); o.w = f2bf(v.w);
    ((ushort4*)xb)[i] = o;
    return;
  }
  __shared__ u16 tile[32][33];
  const int tx = threadIdx.x & 31, ty = threadIdx.x >> 5;
  const float* in;
  u16* outp;
  int lda, ldo, c0, r0;
  if (bid < 11264) {
    const int id = bid - 8192;  // proj_w [1024][3072] -> wt [3072][1024]
    c0 = (id % 96) * 32; r0 = (id / 96) * 32;
    in = pw; outp = wt; lda = 3072; ldo = 1024;
  } else {
    const int id = bid - 11264;  // out_w [1024][1024] -> owt [1024][1024]
    c0 = (id % 32) * 32; r0 = (id / 32) * 32;
    in = ow; outp = owt; lda = 1024; ldo = 1024;
  }
#pragma unroll
  for (int i = 0; i < 4; ++i)
    tile[ty + i * 8][tx] = f2bf(in[(size_t)(r0 + ty + i * 8) * lda + c0 + tx]);
  __syncthreads();
#pragma unroll
  for (int i = 0; i < 4; ++i)
    outp[(size_t)(c0 + ty + i * 8) * ldo + r0 + tx] = tile[tx][ty + i * 8];
}

// ---------------- bit-pack mask: 32 int32 -> 1 u32 word ----------------
__global__ __launch_bounds__(256) void k_bitpack(const int* __restrict__ mask,
                                                 u32* __restrict__ mbits) {
  const size_t w = (size_t)blockIdx.x * 256 + threadIdx.x;
  const int* p = mask + w * 32;
  u32 bits = 0;
#pragma unroll
  for (int j = 0; j < 8; ++j) {
    const int4 v = ((const int4*)p)[j];
    bits |= (u32)(v.x & 1) << (j * 4 + 0);
    bits |= (u32)(v.y & 1) << (j * 4 + 1);
    bits |= (u32)(v.z & 1) << (j * 4 + 2);
    bits |= (u32)(v.w & 1) << (j * 4 + 3);
  }
  mbits[w] = bits;
}

// ---------------- BT GEMM: C[M,N] = A[M,K] * Bt[N,K]^T  (bf16 in, fp32 acc)
// 128x128 tile, BK=64, XOR-swizzled LDS (chunk slot = logical ^ (row&7)).
// MODE 0: +bias[col]; cols<1024 scaled by 1/32 (q prescale); write bf16 (qkv)
// MODE 1: mask(bitpacked)+exp -> bf16 P
// MODE 2: ones-MFMA row sums; v/rowsum + bias[col] -> fp32 (final out)
// MODE 3: transposed bf16 write: C^T stored with ldc = M-dim stride (U -> Ut)
template <int MODE>
__global__ __launch_bounds__(256) void gemm_bt(
    const u16* __restrict__ A, long lda, long bsA,
    const u16* __restrict__ Bt, long ldb, long bsB,
    void* __restrict__ C, long ldc, long bsC,
    int M, int N, int K,
    const float* __restrict__ bias, const u32* __restrict__ mbits) {
  __shared__ u16 As[128 * 64];  // 16 KB, row stride 64 u16, 8-u16 chunks swizzled
  __shared__ u16 Bs[128 * 64];

  const int b = blockIdx.z;
  const int m0 = blockIdx.y * 128, n0 = blockIdx.x * 128;
  const int lane = threadIdx.x & 63;
  const int w = threadIdx.x >> 6;
  const int wr = w >> 1, wc = w & 1;

  // staging: one async16 call covers 8 rows x 64 u16; chunk slot = logical ^ (row&7)
  const int srow = lane >> 3;
  const int scol = ((lane & 7) ^ ((lane >> 3) & 7)) * 8;
  const u16* pa = A + (size_t)b * bsA + (size_t)(m0 + srow) * lda + scol;
  const u16* pb = Bt + (size_t)b * bsB + (size_t)(n0 + srow) * ldb + scol;

  // fragment geometry: lane m=lane&15 holds 8 k at k0=(lane>>4)*8; phys chunk = l^(m&7)
  const int m_l = lane & 15, q = lane >> 4, m7 = m_l & 7;
  const int offs[2] = {(q ^ m7) * 8, ((4 + q) ^ m7) * 8};

  f32x4 acc[4][4] = {};
  f32x4 accs[4] = {};  // MODE 2: row-sum accumulator (C layout)
  bf16x8 ones;
#pragma unroll
  for (int e = 0; e < 8; ++e) ones[e] = (__bf16)1.0f;

  for (int kt = 0; kt < K; kt += 64) {
    __syncthreads();
#pragma unroll
    for (int g = 0; g < 4; ++g) {
      const int c = w * 4 + g;
      async16(pa + (size_t)(c * 8) * lda, As + c * 512);
      async16(pb + (size_t)(c * 8) * ldb, Bs + c * 512);
    }
    __syncthreads();
#pragma unroll
    for (int s = 0; s < 2; ++s) {
      bf16x8 af[4], bfr[4];
#pragma unroll
      for (int t = 0; t < 4; ++t)
        af[t] = *(const bf16x8*)(As + (wr * 64 + t * 16 + m_l) * 64 + offs[s]);
#pragma unroll
      for (int t = 0; t < 4; ++t)
        bfr[t] = *(const bf16x8*)(Bs + (wc * 64 + t * 16 + m_l) * 64 + offs[s]);
#pragma unroll
      for (int mt = 0; mt < 4; ++mt)
#pragma unroll
        for (int nt = 0; nt < 4; ++nt)
          acc[mt][nt] = __builtin_amdgcn_mfma_f32_16x16x32_bf16(af[mt], bfr[nt], acc[mt][nt], 0, 0, 0);
      if constexpr (MODE == 2) {
#pragma unroll
        for (int mt = 0; mt < 4; ++mt)
          accs[mt] = __builtin_amdgcn_mfma_f32_16x16x32_bf16(af[mt], ones, accs[mt], 0, 0, 0);
      }
    }
    pa += 64;
    pb += 64;
  }

  // MODE 1: stage this block's mask bits (128 rows x 4 words) into LDS
  if constexpr (MODE == 1) {
    __syncthreads();
    const int rl = threadIdx.x >> 1, pr = threadIdx.x & 1;
    const uint2 v = *(const uint2*)(mbits + ((size_t)(b * M + m0 + rl)) * (N >> 5) + (n0 >> 5) + pr * 2);
    ((u32*)As)[rl * 4 + pr * 2] = v.x;
    ((u32*)As)[rl * 4 + pr * 2 + 1] = v.y;
    __syncthreads();
  }

  float rinv[4][4];
  if constexpr (MODE == 2) {
#pragma unroll
    for (int mt = 0; mt < 4; ++mt)
#pragma unroll
      for (int r = 0; r < 4; ++r) rinv[mt][r] = 1.0f / accs[mt][r];
  }

  // epilogue: C/D layout col=lane&15, row=(lane>>4)*4+reg
#pragma unroll
  for (int mt = 0; mt < 4; ++mt) {
#pragma unroll
    for (int nt = 0; nt < 4; ++nt) {
      const int col = n0 + wc * 64 + nt * 16 + m_l;
      const int row0 = m0 + wr * 64 + mt * 16 + q * 4;
      if constexpr (MODE == 3) {
        // store C^T: Ut[col][row0..row0+3], packed 8B
        ushort4 o;
        o.x = f2bf(acc[mt][nt][0]); o.y = f2bf(acc[mt][nt][1]);
        o.z = f2bf(acc[mt][nt][2]); o.w = f2bf(acc[mt][nt][3]);
        *(ushort4*)((u16*)C + (size_t)b * bsC + (size_t)col * ldc + row0) = o;
      } else {
#pragma unroll
        for (int r = 0; r < 4; ++r) {
          const int row = row0 + r;
          float v = acc[mt][nt][r];
          if constexpr (MODE == 0) {
            v += bias[col];
            if (col < 1024) v *= 0.03125f;
            ((u16*)C)[(size_t)b * bsC + (size_t)row * ldc + col] = f2bf(v);
          } else if constexpr (MODE == 1) {
            const int cl = wc * 64 + nt * 16 + m_l;
            const int rl = wr * 64 + mt * 16 + q * 4 + r;
            const u32 wb = ((const u32*)As)[rl * 4 + (cl >> 5)];
            v = ((wb >> (cl & 31)) & 1u) ? __expf(fminf(v, 30.f)) : 0.f;
            ((u16*)C)[(size_t)b * bsC + (size_t)row * ldc + col] = f2bf(v);
          } else if constexpr (MODE == 2) {
            v = v * rinv[mt][r] + bias[col];
            ((float*)C)[(size_t)b * bsC + (size_t)row * ldc + col] = v;
          }
        }
      }
    }
  }
}

extern "C" void kernel_launch(void* const* d_in, const int* in_sizes, int n_in,
                              void* d_out, int out_size, void* d_ws, size_t ws_size,
                              hipStream_t stream) {
  const float* x = (const float*)d_in[0];
  const int* mask = (const int*)d_in[1];
  const float* proj_w = (const float*)d_in[2];
  const float* proj_b = (const float*)d_in[3];
  const float* out_w = (const float*)d_in[4];
  const float* out_b = (const float*)d_in[5];
  float* out = (float*)d_out;

  // workspace layout (bytes); peak ~104 MB
  char* ws = (char*)d_ws;
  u16* xb = (u16*)(ws);                      // 16.8 MB [8192][1024]; Ut aliases after qkv
  u16* wt = (u16*)(ws + 16777216);           // 6.3 MB  [3072][1024]; mbits aliases after qkv
  u16* owt = (u16*)(ws + 23068672);          // 2.1 MB  [1024][1024]
  u16* qkv = (u16*)(ws + 25165824);          // 50.3 MB [8192][3072]
  u16* P = (u16*)(ws + 75497472);            // 33.6 MB [4][2048][2048]
  u16* Ut = (u16*)xb;                        // 16.8 MB [4][1024][2048] (U^T = (V·W)^T)
  u32* mbits = (u32*)wt;                     // 2.1 MB

  // 1. prep: x->bf16, proj_w^T, out_w^T (one dispatch)
  k_prep<<<12288, 256, 0, stream>>>(x, xb, proj_w, wt, out_w, owt);
  // 2. qkv = x @ proj_w + b  (q part prescaled by 1/32)
  gemm_bt<0><<<dim3(24, 64, 1), 256, 0, stream>>>(xb, 1024, 0, wt, 1024, 0, qkv, 3072, 0,
                                                  8192, 3072, 1024, proj_b, nullptr);
  // 3. mask -> bit-packed (overlays wt, dead after step 2)
  k_bitpack<<<2048, 256, 0, stream>>>(mask, mbits);
  // 4. P = mask ? exp(q k^T / sqrt(E)) : 0
  gemm_bt<1><<<dim3(16, 16, 4), 256, 0, stream>>>(
      qkv, 3072, (long)2048 * 3072, qkv + 1024, 3072, (long)2048 * 3072,
      P, 2048, (long)2048 * 2048, 2048, 2048, 1024, nullptr, mbits);
  // 5. Ut = (V @ out_w)^T  (V read in natural layout from qkv; transposed store)
  gemm_bt<3><<<dim3(8, 16, 4), 256, 0, stream>>>(
      qkv + 2048, 3072, (long)2048 * 3072, owt, 1024, 0,
      Ut, 2048, (long)1024 * 2048, 2048, 1024, 1024, nullptr, nullptr);
  // 6. out = P @ U / rowsum(P) + out_b  (rowsum via ones-MFMA; fp32)
  gemm_bt<2><<<dim3(8, 16, 4), 256, 0, stream>>>(
      P, 2048, (long)2048 * 2048, Ut, 2048, (long)1024 * 2048,
      out, 1024, (long)2048 * 1024, 2048, 1024, 2048, out_b, nullptr);
}

// Round 5
// 341.955 us; speedup vs baseline: 1.2850x; 1.0100x over previous
//
#include <hip/hip_runtime.h>
#include <cstdint>

typedef unsigned short u16;
typedef uint32_t u32;
typedef __bf16 bf16x8 __attribute__((ext_vector_type(8)));
typedef float f32x4 __attribute__((ext_vector_type(4)));

__device__ __forceinline__ u16 f2bf(float f) {
  unsigned u = __float_as_uint(f);
  u += 0x7fffu + ((u >> 16) & 1u);
  return (u16)(u >> 16);
}

__device__ __forceinline__ void async16(const void* g, void* l) {
  __builtin_amdgcn_global_load_lds(
      (const __attribute__((address_space(1))) uint32_t*)g,
      (__attribute__((address_space(3))) uint32_t*)l, 16, 0, 0);
}

// --- fused prep: x->bf16 | proj_w^T | out_w^T | mask bitpack (one dispatch) ---
// grid: [0,8192) cvt; [8192,11264) pw^T; [11264,12288) ow^T; [12288,14336) bitpack
__global__ __launch_bounds__(256) void k_prep(const float* __restrict__ x, u16* __restrict__ xb,
                                              const float* __restrict__ pw, u16* __restrict__ wt,
                                              const float* __restrict__ ow, u16* __restrict__ owt,
                                              const int* __restrict__ mask, u32* __restrict__ mbits) {
  const int bid = blockIdx.x;
  if (bid < 8192) {
    const int i = bid * 256 + threadIdx.x;
    const float4 v = ((const float4*)x)[i];
    ushort4 o;
    o.x = f2bf(v.x); o.y = f2bf(v.y); o.z = f2bf(v.z); o.w = f2bf(v.w);
    ((ushort4*)xb)[i] = o;
    return;
  }
  if (bid >= 12288) {
    const size_t w = (size_t)(bid - 12288) * 256 + threadIdx.x;
    const int* p = mask + w * 32;
    u32 bits = 0;
#pragma unroll
    for (int j = 0; j < 8; ++j) {
      const int4 v = ((const int4*)p)[j];
      bits |= (u32)(v.x & 1) << (j * 4 + 0);
      bits |= (u32)(v.y & 1) << (j * 4 + 1);
      bits |= (u32)(v.z & 1) << (j * 4 + 2);
      bits |= (u32)(v.w & 1) << (j * 4 + 3);
    }
    mbits[w] = bits;
    return;
  }
  __shared__ u16 tile[32][33];
  const int tx = threadIdx.x & 31, ty = threadIdx.x >> 5;
  const float* in;
  u16* outp;
  int lda, ldo, c0, r0;
  if (bid < 11264) {
    const int id = bid - 8192;  // proj_w [1024][3072] -> wt [3072][1024]
    c0 = (id % 96) * 32; r0 = (id / 96) * 32;
    in = pw; outp = wt; lda = 3072; ldo = 1024;
  } else {
    const int id = bid - 11264;  // out_w [1024][1024] -> owt [1024][1024]
    c0 = (id % 32) * 32; r0 = (id / 32) * 32;
    in = ow; outp = owt; lda = 1024; ldo = 1024;
  }
#pragma unroll
  for (int i = 0; i < 4; ++i)
    tile[ty + i * 8][tx] = f2bf(in[(size_t)(r0 + ty + i * 8) * lda + c0 + tx]);
  __syncthreads();
#pragma unroll
  for (int i = 0; i < 4; ++i)
    outp[(size_t)(c0 + ty + i * 8) * ldo + r0 + tx] = tile[tx][ty + i * 8];
}

// ---------------- BT GEMM: C[M,N] = A[M,K] * Bt[N,K]^T  (bf16 in, fp32 acc)
// TM x 128 tile (TM=128 or 64), BK=64, XOR-swizzled LDS.
// MODE 0: +bias[col]; cols<1024 scaled by 1/32; write bf16 (qkv)
// MODE 1: mask(bitpacked)+exp -> bf16 P              (TM=128 only)
// MODE 2: ones-MFMA row sums; v/rowsum + bias -> fp32 (final out)
// MODE 3: transposed bf16 write (U -> Ut)
template <int MODE, int TM>
__global__ __launch_bounds__(256) void gemm_bt(
    const u16* __restrict__ A, long lda, long bsA,
    const u16* __restrict__ Bt, long ldb, long bsB,
    void* __restrict__ C, long ldc, long bsC,
    int M, int N, int K,
    const float* __restrict__ bias, const u32* __restrict__ mbits) {
  constexpr int MT = TM / 32;        // 16-row tiles per wave in M
  constexpr int ACALLS = TM / 8;     // async16 calls for A tile
  constexpr int NC = (TM + 128) / 32;  // staging calls per wave
  __shared__ u16 As[TM * 64];
  __shared__ u16 Bs[128 * 64];

  const int b = blockIdx.z;
  const int m0 = blockIdx.y * TM, n0 = blockIdx.x * 128;
  const int lane = threadIdx.x & 63;
  const int w = threadIdx.x >> 6;
  const int wr = w >> 1, wc = w & 1;

  // staging: one async16 call covers 8 rows x 64 u16; chunk slot = logical ^ (row&7)
  const int srow = lane >> 3;
  const int scol = ((lane & 7) ^ ((lane >> 3) & 7)) * 8;
  const u16* pa = A + (size_t)b * bsA + (size_t)(m0 + srow) * lda + scol;
  const u16* pb = Bt + (size_t)b * bsB + (size_t)(n0 + srow) * ldb + scol;

  // fragment geometry: lane m=lane&15 holds 8 k at k0=(lane>>4)*8; phys chunk = l^(m&7)
  const int m_l = lane & 15, q = lane >> 4, m7 = m_l & 7;
  const int offs[2] = {(q ^ m7) * 8, ((4 + q) ^ m7) * 8};

  f32x4 acc[MT][4] = {};
  f32x4 accs[MT] = {};  // MODE 2: row-sum accumulator (C layout)
  bf16x8 ones;
#pragma unroll
  for (int e = 0; e < 8; ++e) ones[e] = (__bf16)1.0f;

  for (int kt = 0; kt < K; kt += 64) {
    __syncthreads();
#pragma unroll
    for (int g = 0; g < NC; ++g) {
      const int idx = w * NC + g;
      if (idx < ACALLS)
        async16(pa + (size_t)(idx * 8) * lda, As + idx * 512);
      else
        async16(pb + (size_t)((idx - ACALLS) * 8) * ldb, Bs + (idx - ACALLS) * 512);
    }
    __syncthreads();
#pragma unroll
    for (int s = 0; s < 2; ++s) {
      bf16x8 af[MT], bfr[4];
#pragma unroll
      for (int t = 0; t < MT; ++t)
        af[t] = *(const bf16x8*)(As + (wr * (TM / 2) + t * 16 + m_l) * 64 + offs[s]);
#pragma unroll
      for (int t = 0; t < 4; ++t)
        bfr[t] = *(const bf16x8*)(Bs + (wc * 64 + t * 16 + m_l) * 64 + offs[s]);
#pragma unroll
      for (int mt = 0; mt < MT; ++mt)
#pragma unroll
        for (int nt = 0; nt < 4; ++nt)
          acc[mt][nt] = __builtin_amdgcn_mfma_f32_16x16x32_bf16(af[mt], bfr[nt], acc[mt][nt], 0, 0, 0);
      if constexpr (MODE == 2) {
#pragma unroll
        for (int mt = 0; mt < MT; ++mt)
          accs[mt] = __builtin_amdgcn_mfma_f32_16x16x32_bf16(af[mt], ones, accs[mt], 0, 0, 0);
      }
    }
    pa += 64;
    pb += 64;
  }

  // MODE 1: stage this block's mask bits (128 rows x 4 words) into LDS
  if constexpr (MODE == 1) {
    __syncthreads();
    const int rl = threadIdx.x >> 1, pr = threadIdx.x & 1;
    const uint2 v = *(const uint2*)(mbits + ((size_t)(b * M + m0 + rl)) * (N >> 5) + (n0 >> 5) + pr * 2);
    ((u32*)As)[rl * 4 + pr * 2] = v.x;
    ((u32*)As)[rl * 4 + pr * 2 + 1] = v.y;
    __syncthreads();
  }

  float rinv[MT][4];
  if constexpr (MODE == 2) {
#pragma unroll
    for (int mt = 0; mt < MT; ++mt)
#pragma unroll
      for (int r = 0; r < 4; ++r) rinv[mt][r] = 1.0f / accs[mt][r];
  }

  // epilogue: C/D layout col=lane&15, row=(lane>>4)*4+reg
#pragma unroll
  for (int mt = 0; mt < MT; ++mt) {
#pragma unroll
    for (int nt = 0; nt < 4; ++nt) {
      const int col = n0 + wc * 64 + nt * 16 + m_l;
      const int row0 = m0 + wr * (TM / 2) + mt * 16 + q * 4;
      if constexpr (MODE == 3) {
        ushort4 o;
        o.x = f2bf(acc[mt][nt][0]); o.y = f2bf(acc[mt][nt][1]);
        o.z = f2bf(acc[mt][nt][2]); o.w = f2bf(acc[mt][nt][3]);
        *(ushort4*)((u16*)C + (size_t)b * bsC + (size_t)col * ldc + row0) = o;
      } else {
#pragma unroll
        for (int r = 0; r < 4; ++r) {
          const int row = row0 + r;
          float v = acc[mt][nt][r];
          if constexpr (MODE == 0) {
            v += bias[col];
            if (col < 1024) v *= 0.03125f;
            ((u16*)C)[(size_t)b * bsC + (size_t)row * ldc + col] = f2bf(v);
          } else if constexpr (MODE == 1) {
            const int cl = wc * 64 + nt * 16 + m_l;
            const int rl = wr * 64 + mt * 16 + q * 4 + r;
            const u32 wb = ((const u32*)As)[rl * 4 + (cl >> 5)];
            v = ((wb >> (cl & 31)) & 1u) ? __expf(fminf(v, 30.f)) : 0.f;
            ((u16*)C)[(size_t)b * bsC + (size_t)row * ldc + col] = f2bf(v);
          } else if constexpr (MODE == 2) {
            v = v * rinv[mt][r] + bias[col];
            ((float*)C)[(size_t)b * bsC + (size_t)row * ldc + col] = v;
          }
        }
      }
    }
  }
}

extern "C" void kernel_launch(void* const* d_in, const int* in_sizes, int n_in,
                              void* d_out, int out_size, void* d_ws, size_t ws_size,
                              hipStream_t stream) {
  const float* x = (const float*)d_in[0];
  const int* mask = (const int*)d_in[1];
  const float* proj_w = (const float*)d_in[2];
  const float* proj_b = (const float*)d_in[3];
  const float* out_w = (const float*)d_in[4];
  const float* out_b = (const float*)d_in[5];
  float* out = (float*)d_out;

  // workspace layout (bytes); peak ~104 MB
  char* ws = (char*)d_ws;
  u16* xb = (u16*)(ws);                      // 16.8 MB [8192][1024]; Ut aliases after qkv
  u16* wt = (u16*)(ws + 16777216);           // 6.3 MB  [3072][1024]
  u16* owt = (u16*)(ws + 23068672);          // 2.1 MB  [1024][1024]
  u16* qkv = (u16*)(ws + 25165824);          // 50.3 MB [8192][3072]
  u16* P = (u16*)(ws + 75497472);            // 33.6 MB [4][2048][2048]
  u32* mbits = (u32*)(ws + 109051904);       // 2.1 MB
  u16* Ut = (u16*)xb;                        // 16.8 MB [4][1024][2048] (U^T = (V·W)^T)

  // 1. prep: x->bf16, proj_w^T, out_w^T, mask bitpack (one dispatch)
  k_prep<<<14336, 256, 0, stream>>>(x, xb, proj_w, wt, out_w, owt, mask, mbits);
  // 2. qkv = x @ proj_w + b  (q part prescaled by 1/32)
  gemm_bt<0, 128><<<dim3(24, 64, 1), 256, 0, stream>>>(xb, 1024, 0, wt, 1024, 0, qkv, 3072, 0,
                                                       8192, 3072, 1024, proj_b, nullptr);
  // 3. P = mask ? exp(q k^T / sqrt(E)) : 0
  gemm_bt<1, 128><<<dim3(16, 16, 4), 256, 0, stream>>>(
      qkv, 3072, (long)2048 * 3072, qkv + 1024, 3072, (long)2048 * 3072,
      P, 2048, (long)2048 * 2048, 2048, 2048, 1024, nullptr, mbits);
  // 4. Ut = (V @ out_w)^T   (TM=64 -> 1024 blocks)
  gemm_bt<3, 64><<<dim3(8, 32, 4), 256, 0, stream>>>(
      qkv + 2048, 3072, (long)2048 * 3072, owt, 1024, 0,
      Ut, 2048, (long)1024 * 2048, 2048, 1024, 1024, nullptr, nullptr);
  // 5. out = P @ U / rowsum(P) + out_b   (TM=64 -> 1024 blocks)
  gemm_bt<2, 64><<<dim3(8, 32, 4), 256, 0, stream>>>(
      P, 2048, (long)2048 * 2048, Ut, 2048, (long)1024 * 2048,
      out, 1024, (long)2048 * 1024, 2048, 1024, 2048, out_b, nullptr);
}